// Round 4
// baseline (568.718 us; speedup 1.0000x reference)
//
#include <hip/hip_runtime.h>
#include <hip/hip_bf16.h>

// GraphPolicyNetwork: 2-layer GraphSAGE (rank-1 weights -> scalar edge passes)
// + dense head [64x4096]@[4096x4096].
//
// Round-3 forensics: inputs AND outputs are fp32 (error 1.79 == harness
// reading my packed bf16 writes as fp32; rounds 1-2 NaN == reading fp32
// inputs as bf16). Outputs now written fp32. Runtime input-dtype probe kept
// (cheap, covers a bf16-converted dataset variant).
// Workspace: 4 fp32 slots of NTOT = 4.19 MB.

typedef __hip_bfloat16 bf16;

#define NTOT (64 * 4096)      // 262144 total nodes
#define NHID 128
#define GK   4096             // GEMM K == N_NODES
#define KCH  256              // K per chunk
#define KCHUNKS 16

__device__ __forceinline__ float bits2f(unsigned short h) {
    return __uint_as_float(((unsigned)h) << 16);   // bf16 -> fp32 exact
}

// Wave-uniform runtime dtype probe on first 512 shorts of w3.
// bf16 N(0,1/64): exponents in [96,134] -> ~0 bad lanes.
// fp32 bit patterns: low-half shorts have ~uniform exponents -> ~all lanes bad.
__device__ __forceinline__ int detect_bf16(const unsigned short* __restrict__ u) {
    int lane = threadIdx.x & 63;
    int bad = 0;
#pragma unroll
    for (int j = 0; j < 8; ++j) {
        unsigned short h = u[lane * 8 + j];
        int e = (h >> 7) & 0xFF;
        bad += (((h & 0x7FFFu) != 0) && (e < 96 || e > 134)) ? 1 : 0;
    }
    unsigned long long m = __ballot(bad > 0);
    return __popcll(m) < 16;    // few bad lanes => genuine bf16
}

__device__ __forceinline__ float ldf(const void* p, int i, int isbf) {
    return isbf ? bits2f(((const unsigned short*)p)[i]) : ((const float*)p)[i];
}

__device__ __forceinline__ float fast_tanh(float x) {
    float ax = fabsf(x);
    float t  = __expf(-2.0f * ax);
    float r  = (1.0f - t) / (1.0f + t);
    return copysignf(r, x);
}

// ---- edge pass 1: agg[dst] += f[src]; deg[dst] += 1 ----
__global__ void edge_pass1(const int* __restrict__ src, const int* __restrict__ dst,
                           const void* __restrict__ nf,
                           const unsigned short* __restrict__ w3u,
                           float* __restrict__ agg, float* __restrict__ deg,
                           int n_edges) {
    int isbf = detect_bf16(w3u);
    int e = blockIdx.x * blockDim.x + threadIdx.x;
    if (e >= n_edges) return;
    int s = src[e], d = dst[e];
    atomicAdd(&agg[d], ldf(nf, s, isbf));
    atomicAdd(&deg[d], 1.0f);
}

// ---- node pass 1: s0[v]: agg in -> selfpart out (in-place); sp[v] out ----
__global__ void node1(const void* __restrict__ nf,
                      const unsigned short* __restrict__ w3u,
                      float* s0, const float* __restrict__ deg,
                      const void* __restrict__ w_s1, const void* __restrict__ w_n1,
                      const void* __restrict__ bb1,
                      const void* __restrict__ w_s2, const void* __restrict__ w_n2,
                      float* __restrict__ sp) {
    int isbf = detect_bf16(w3u);
    __shared__ float lws1[NHID], lwn1[NHID], lb1[NHID], lws2[NHID], lwn2[NHID];
    int tid = threadIdx.x;
    if (tid < NHID) {
        lws1[tid] = ldf(w_s1, tid, isbf);
        lwn1[tid] = ldf(w_n1, tid, isbf);
        lb1[tid]  = ldf(bb1,  tid, isbf);
        lws2[tid] = ldf(w_s2, tid, isbf);
        lwn2[tid] = ldf(w_n2, tid, isbf);
    }
    __syncthreads();
    int v = blockIdx.x * blockDim.x + tid;
    float f  = ldf(nf, v, isbf);
    float hn = s0[v] / fmaxf(deg[v], 1.0f);
    float a = 0.0f, s = 0.0f;
#pragma unroll 8
    for (int j = 0; j < NHID; ++j) {
        float t = fast_tanh(fmaf(f, lws1[j], fmaf(hn, lwn1[j], lb1[j])));
        a = fmaf(t, lws2[j], a);
        s = fmaf(t, lwn2[j], s);
    }
    s0[v] = a;      // selfpart overwrites agg (same index, read-before-write)
    sp[v] = s;
}

// ---- edge pass 2: agg2[dst] += sp[src] (all fp32 internal) ----
__global__ void edge_pass2(const int* __restrict__ src, const int* __restrict__ dst,
                           const float* __restrict__ sp, float* __restrict__ agg2,
                           int n_edges) {
    int e = blockIdx.x * blockDim.x + threadIdx.x;
    if (e >= n_edges) return;
    atomicAdd(&agg2[dst[e]], sp[src[e]]);
}

// ---- node pass 2: out1 (fp32); h2t (into sp's slot, sp dead);
//      seed out2[v] = b3[v&4095] directly in d_out (fp32) ----
__global__ void node2(const unsigned short* __restrict__ w3u,
                      const float* __restrict__ s0, const float* __restrict__ agg2,
                      const float* __restrict__ deg,
                      const void* __restrict__ b2p, const void* __restrict__ b3p,
                      float* __restrict__ out1, float* __restrict__ h2t,
                      float* __restrict__ out2) {
    int isbf = detect_bf16(w3u);
    int v = blockIdx.x * blockDim.x + threadIdx.x;
    float o = s0[v] + agg2[v] / fmaxf(deg[v], 1.0f) + ldf(b2p, 0, isbf);
    out1[v] = o;
    int r = v >> 12;     // graph (row) index 0..63
    int k = v & 4095;    // node-in-graph (K) index
    h2t[k * 64 + r] = fast_tanh(o);
    out2[v] = ldf(b3p, v & 4095, isbf);   // bias seed for GEMM accumulation
}

// ---- GEMM: out2[r][n] += sum_{k in chunk} h2t[k][r] * w3[k][n] ----
// One thread per column n, 64 row accumulators (A values wave-uniform,
// scalarizable); K-split accumulates via non-returning fp32 atomicAdd
// directly into d_out's second half (b3-seeded by node2).
__global__ void __launch_bounds__(256) gemm_head(const float* __restrict__ h2t,
                                                 const void* __restrict__ w3,
                                                 float* __restrict__ out2) {
    int isbf = detect_bf16((const unsigned short*)w3);
    int n  = blockIdx.x * 256 + threadIdx.x;
    int k0 = blockIdx.y * KCH;
    float acc[64];
#pragma unroll
    for (int r = 0; r < 64; ++r) acc[r] = 0.0f;

    if (isbf) {
        const unsigned short* w = (const unsigned short*)w3;
        for (int k = k0; k < k0 + KCH; ++k) {
            float bv = bits2f(w[(size_t)k * GK + n]);
            const float* Ak = h2t + k * 64;
#pragma unroll
            for (int r = 0; r < 64; ++r) acc[r] = fmaf(Ak[r], bv, acc[r]);
        }
    } else {
        const float* w = (const float*)w3;
        for (int k = k0; k < k0 + KCH; ++k) {
            float bv = w[(size_t)k * GK + n];
            const float* Ak = h2t + k * 64;
#pragma unroll
            for (int r = 0; r < 64; ++r) acc[r] = fmaf(Ak[r], bv, acc[r]);
        }
    }
#pragma unroll
    for (int r = 0; r < 64; ++r) atomicAdd(&out2[r * GK + n], acc[r]);
}

extern "C" void kernel_launch(void* const* d_in, const int* in_sizes, int n_in,
                              void* d_out, int out_size, void* d_ws, size_t ws_size,
                              hipStream_t stream) {
    const void* nf  = d_in[0];
    const int*  src = (const int*)d_in[1];
    const int*  dst = (const int*)d_in[2];
    const void* ws1 = d_in[3];
    const void* wn1 = d_in[4];
    const void* b1  = d_in[5];
    const void* ws2 = d_in[6];
    const void* wn2 = d_in[7];
    const void* b2  = d_in[8];
    const void* w3  = d_in[9];
    const void* b3  = d_in[10];
    const unsigned short* w3u = (const unsigned short*)w3;
    float* out1 = (float*)d_out;
    float* out2 = (float*)d_out + NTOT;

    int n_edges = in_sizes[1];

    float* ws = (float*)d_ws;
    float* S0 = ws;            // agg -> selfpart
    float* S1 = ws + 1 * NTOT; // deg
    float* S2 = ws + 2 * NTOT; // agg2
    float* S3 = ws + 3 * NTOT; // sp -> h2t (K-major, 64 rows contiguous per k)

    // zero S0 (agg), S1 (deg), S2 (agg2)
    hipMemsetAsync(S0, 0, (size_t)3 * NTOT * sizeof(float), stream);

    int eb = (n_edges + 255) / 256;
    edge_pass1<<<eb, 256, 0, stream>>>(src, dst, nf, w3u, S0, S1, n_edges);
    node1<<<NTOT / 256, 256, 0, stream>>>(nf, w3u, S0, S1, ws1, wn1, b1, ws2, wn2, S3);
    edge_pass2<<<eb, 256, 0, stream>>>(src, dst, S3, S2, n_edges);
    node2<<<NTOT / 256, 256, 0, stream>>>(w3u, S0, S2, S1, b2, b3, out1, S3, out2);
    gemm_head<<<dim3(GK / 256, KCHUNKS), 256, 0, stream>>>(S3, w3, out2);
}

// Round 6
// 472.899 us; speedup vs baseline: 1.2026x; 1.2026x over previous
//
#include <hip/hip_runtime.h>

// GraphPolicyNetwork: 2-layer GraphSAGE (rank-1 weights -> scalar edge passes)
// + dense head [64x4096]@[4096x4096]. All tensors fp32 (proven round 4).
//
// R4 post-mortem: device-scope atomics run at ~19.4 G/s with 32 B fabric
// write-through each (edge_pass1: 206 us, WRITE_SIZE 131 MB for a 2 MB
// accumulator). Fix: per-XCD replica accumulators updated with
// WORKGROUP-scope atomics (execute in the XCD's own L2; replica index =
// HW_REG_XCC_ID so no two XCDs share an address; kernel-end flush
// publishes). GEMM K-split now stores partials (no atomics) + reduce.
// Fast path needs exactly 20 MB of d_ws; falls back to the proven R4
// device-atomic pipeline if ws_size is smaller.
// (R5 was this same design; it died on a << precedence bug in the ws
// pointer arithmetic, fixed here.)

#define NTOT (64 * 4096)      // 262144 total nodes
#define NHID 128
#define GK   4096             // GEMM K == N_NODES
#define KCH  256              // K per chunk
#define KCHUNKS 16
#define NXCD 8
#define MASK44 ((1ULL << 44) - 1)

typedef unsigned long long u64;

__device__ __forceinline__ int xcc_id() {
    // s_getreg_b32 hwreg(HW_REG_XCC_ID=20, offset 0, size 32):
    // simm16 = 20 | (31 << 11) = 63508. Wave-uniform; block lives on one XCD.
    return (int)(__builtin_amdgcn_s_getreg(63508) & 7u);
}

__device__ __forceinline__ float fast_tanh(float x) {
    float ax = fabsf(x);
    float t  = __expf(-2.0f * ax);
    float r  = (1.0f - t) / (1.0f + t);
    return copysignf(r, x);
}

// ======================= FAST PATH (ws >= 20 MB) ==========================

// ---- edge pass 1: packed (deg | fixed-point sum) into per-XCD replica ----
__global__ void edge_pass1_x(const int* __restrict__ src, const int* __restrict__ dst,
                             const float* __restrict__ nf, u64* __restrict__ rep,
                             int n_edges) {
    u64* myrep = rep + (size_t)xcc_id() * NTOT;
    int e = blockIdx.x * blockDim.x + threadIdx.x;
    if (e >= n_edges) return;
    float v = nf[src[e]];
    // (v+8) in (2,14); field = (v+8)*2^32; per-replica sum < 64*14*2^32 < 2^42.
    u64 enc = (1ULL << 44) +
              (u64)(long long)llrintf(fmaf(v, 4294967296.0f, 8.0f * 4294967296.0f));
    __hip_atomic_fetch_add(&myrep[dst[e]], enc, __ATOMIC_RELAXED,
                           __HIP_MEMORY_SCOPE_WORKGROUP);
}

// ---- node pass 1: decode replicas; selfpart, sp, deg out ----
__global__ void node1_x(const float* __restrict__ nf, const u64* __restrict__ rep,
                        const float* __restrict__ w_s1, const float* __restrict__ w_n1,
                        const float* __restrict__ bb1,
                        const float* __restrict__ w_s2, const float* __restrict__ w_n2,
                        float* __restrict__ degf, float* __restrict__ selfp,
                        float* __restrict__ sp) {
    __shared__ float lws1[NHID], lwn1[NHID], lb1[NHID], lws2[NHID], lwn2[NHID];
    int tid = threadIdx.x;
    if (tid < NHID) {
        lws1[tid] = w_s1[tid];
        lwn1[tid] = w_n1[tid];
        lb1[tid]  = bb1[tid];
        lws2[tid] = w_s2[tid];
        lwn2[tid] = w_n2[tid];
    }
    __syncthreads();
    int v = blockIdx.x * blockDim.x + tid;
    int degi = 0;
    double sfix = 0.0;
#pragma unroll
    for (int r = 0; r < NXCD; ++r) {
        u64 x = rep[(size_t)r * NTOT + v];
        degi += (int)(x >> 44);
        sfix += (double)(x & MASK44);
    }
    float hsum = (float)(sfix * (1.0 / 4294967296.0) - 8.0 * (double)degi);
    float hn = hsum / fmaxf((float)degi, 1.0f);
    float f = nf[v];
    float a = 0.0f, s = 0.0f;
#pragma unroll 8
    for (int j = 0; j < NHID; ++j) {
        float t = fast_tanh(fmaf(f, lws1[j], fmaf(hn, lwn1[j], lb1[j])));
        a = fmaf(t, lws2[j], a);
        s = fmaf(t, lwn2[j], s);
    }
    degf[v]  = (float)degi;
    selfp[v] = a;
    sp[v]    = s;
}

// ---- edge pass 2: fp32 per-XCD replica accumulation ----
__global__ void edge_pass2_x(const int* __restrict__ src, const int* __restrict__ dst,
                             const float* __restrict__ sp, float* __restrict__ rep2,
                             int n_edges) {
    float* myrep = rep2 + (size_t)xcc_id() * NTOT;
    int e = blockIdx.x * blockDim.x + threadIdx.x;
    if (e >= n_edges) return;
    __hip_atomic_fetch_add(&myrep[dst[e]], sp[src[e]], __ATOMIC_RELAXED,
                           __HIP_MEMORY_SCOPE_WORKGROUP);
}

// ---- node pass 2: out1 (fp32); h2t K-major ----
__global__ void node2_x(const float* __restrict__ selfp, const float* __restrict__ rep2,
                        const float* __restrict__ degf, const float* __restrict__ b2p,
                        float* __restrict__ out1, float* __restrict__ h2t) {
    int v = blockIdx.x * blockDim.x + threadIdx.x;
    float agg2 = 0.0f;
#pragma unroll
    for (int r = 0; r < NXCD; ++r) agg2 += rep2[(size_t)r * NTOT + v];
    float o = selfp[v] + agg2 / fmaxf(degf[v], 1.0f) + b2p[0];
    out1[v] = o;
    int r = v >> 12;     // graph (row) index 0..63
    int k = v & 4095;    // node-in-graph (K) index
    h2t[k * 64 + r] = fast_tanh(o);
}

// ---- GEMM: Cpart[kc][r][n] = sum_{k in chunk} h2t[k][r] * w3[k][n] ----
__global__ void __launch_bounds__(256) gemm_x(const float* __restrict__ h2t,
                                              const float* __restrict__ w3,
                                              float* __restrict__ Cpart) {
    int n  = blockIdx.x * 256 + threadIdx.x;
    int k0 = blockIdx.y * KCH;
    float acc[64];
#pragma unroll
    for (int r = 0; r < 64; ++r) acc[r] = 0.0f;
    for (int k = k0; k < k0 + KCH; ++k) {
        float bv = w3[(size_t)k * GK + n];
        const float* Ak = h2t + k * 64;
#pragma unroll
        for (int r = 0; r < 64; ++r) acc[r] = fmaf(Ak[r], bv, acc[r]);
    }
    float* Cp = Cpart + (size_t)blockIdx.y * NTOT;
#pragma unroll
    for (int r = 0; r < 64; ++r) Cp[r * GK + n] = acc[r];
}

// ---- reduce K-chunk partials + b3 -> out2 ----
__global__ void reduce_x(const float* __restrict__ Cpart, const float* __restrict__ b3,
                         float* __restrict__ out2) {
    int v = blockIdx.x * blockDim.x + threadIdx.x;
    float s = b3[v & 4095];
#pragma unroll
    for (int kc = 0; kc < KCHUNKS; ++kc) s += Cpart[(size_t)kc * NTOT + v];
    out2[v] = s;
}

// ================== FALLBACK PATH (proven R4 pipeline) ====================

__global__ void edge_pass1_f(const int* __restrict__ src, const int* __restrict__ dst,
                             const float* __restrict__ nf, float* __restrict__ agg,
                             float* __restrict__ deg, int n_edges) {
    int e = blockIdx.x * blockDim.x + threadIdx.x;
    if (e >= n_edges) return;
    int s = src[e], d = dst[e];
    atomicAdd(&agg[d], nf[s]);
    atomicAdd(&deg[d], 1.0f);
}

__global__ void node1_f(const float* __restrict__ nf, float* s0,
                        const float* __restrict__ deg,
                        const float* __restrict__ w_s1, const float* __restrict__ w_n1,
                        const float* __restrict__ bb1,
                        const float* __restrict__ w_s2, const float* __restrict__ w_n2,
                        float* __restrict__ sp) {
    __shared__ float lws1[NHID], lwn1[NHID], lb1[NHID], lws2[NHID], lwn2[NHID];
    int tid = threadIdx.x;
    if (tid < NHID) {
        lws1[tid] = w_s1[tid];
        lwn1[tid] = w_n1[tid];
        lb1[tid]  = bb1[tid];
        lws2[tid] = w_s2[tid];
        lwn2[tid] = w_n2[tid];
    }
    __syncthreads();
    int v = blockIdx.x * blockDim.x + tid;
    float f  = nf[v];
    float hn = s0[v] / fmaxf(deg[v], 1.0f);
    float a = 0.0f, s = 0.0f;
#pragma unroll 8
    for (int j = 0; j < NHID; ++j) {
        float t = fast_tanh(fmaf(f, lws1[j], fmaf(hn, lwn1[j], lb1[j])));
        a = fmaf(t, lws2[j], a);
        s = fmaf(t, lwn2[j], s);
    }
    s0[v] = a;
    sp[v] = s;
}

__global__ void edge_pass2_f(const int* __restrict__ src, const int* __restrict__ dst,
                             const float* __restrict__ sp, float* __restrict__ agg2,
                             int n_edges) {
    int e = blockIdx.x * blockDim.x + threadIdx.x;
    if (e >= n_edges) return;
    atomicAdd(&agg2[dst[e]], sp[src[e]]);
}

__global__ void node2_f(const float* __restrict__ s0, const float* __restrict__ agg2,
                        const float* __restrict__ deg, const float* __restrict__ b2p,
                        const float* __restrict__ b3p,
                        float* __restrict__ out1, float* __restrict__ h2t,
                        float* __restrict__ out2) {
    int v = blockIdx.x * blockDim.x + threadIdx.x;
    float o = s0[v] + agg2[v] / fmaxf(deg[v], 1.0f) + b2p[0];
    out1[v] = o;
    int r = v >> 12;
    int k = v & 4095;
    h2t[k * 64 + r] = fast_tanh(o);
    out2[v] = b3p[v & 4095];
}

__global__ void __launch_bounds__(256) gemm_f(const float* __restrict__ h2t,
                                              const float* __restrict__ w3,
                                              float* __restrict__ out2) {
    int n  = blockIdx.x * 256 + threadIdx.x;
    int k0 = blockIdx.y * KCH;
    float acc[64];
#pragma unroll
    for (int r = 0; r < 64; ++r) acc[r] = 0.0f;
    for (int k = k0; k < k0 + KCH; ++k) {
        float bv = w3[(size_t)k * GK + n];
        const float* Ak = h2t + k * 64;
#pragma unroll
        for (int r = 0; r < 64; ++r) acc[r] = fmaf(Ak[r], bv, acc[r]);
    }
#pragma unroll
    for (int r = 0; r < 64; ++r) atomicAdd(&out2[r * GK + n], acc[r]);
}

// ==========================================================================

extern "C" void kernel_launch(void* const* d_in, const int* in_sizes, int n_in,
                              void* d_out, int out_size, void* d_ws, size_t ws_size,
                              hipStream_t stream) {
    const float* nf  = (const float*)d_in[0];
    const int*   src = (const int*)d_in[1];
    const int*   dst = (const int*)d_in[2];
    const float* ws1 = (const float*)d_in[3];
    const float* wn1 = (const float*)d_in[4];
    const float* b1  = (const float*)d_in[5];
    const float* ws2 = (const float*)d_in[6];
    const float* wn2 = (const float*)d_in[7];
    const float* b2  = (const float*)d_in[8];
    const float* w3  = (const float*)d_in[9];
    const float* b3  = (const float*)d_in[10];
    float* out1 = (float*)d_out;
    float* out2 = (float*)d_out + NTOT;

    int n_edges = in_sizes[1];
    int eb = (n_edges + 255) / 256;

    if (ws_size >= (size_t)20 * 1024 * 1024) {
        // -------- fast path: 20 MB layout (parenthesized byte offsets!) ----
        char* base = (char*)d_ws;
        u64*   rep   = (u64*)base;                               // 16 MB
        float* degf  = (float*)(base + (((size_t)16) << 20));    // 1 MB
        float* selfp = (float*)(base + (((size_t)17) << 20));    // 1 MB
        float* sp    = (float*)(base + (((size_t)18) << 20));    // 1 MB
        float* h2t   = (float*)(base + (((size_t)19) << 20));    // 1 MB
        float* rep2  = (float*)base;   // 8 MB, reuses rep after node1
        float* Cpart = (float*)base;   // 16 MB, reuses rep after node2

        (void)hipMemsetAsync(rep, 0, (size_t)NXCD * NTOT * sizeof(u64), stream);
        edge_pass1_x<<<eb, 256, 0, stream>>>(src, dst, nf, rep, n_edges);
        node1_x<<<NTOT / 256, 256, 0, stream>>>(nf, rep, ws1, wn1, b1, ws2, wn2,
                                                degf, selfp, sp);
        (void)hipMemsetAsync(rep2, 0, (size_t)NXCD * NTOT * sizeof(float), stream);
        edge_pass2_x<<<eb, 256, 0, stream>>>(src, dst, sp, rep2, n_edges);
        node2_x<<<NTOT / 256, 256, 0, stream>>>(selfp, rep2, degf, b2, out1, h2t);
        gemm_x<<<dim3(GK / 256, KCHUNKS), 256, 0, stream>>>(h2t, w3, Cpart);
        reduce_x<<<NTOT / 256, 256, 0, stream>>>(Cpart, b3, out2);
    } else {
        // -------- fallback: proven R4 pipeline (4.19 MB) --------
        float* ws = (float*)d_ws;
        float* S0 = ws;            // agg -> selfpart
        float* S1 = ws + 1 * NTOT; // deg
        float* S2 = ws + 2 * NTOT; // agg2
        float* S3 = ws + 3 * NTOT; // sp -> h2t

        (void)hipMemsetAsync(S0, 0, (size_t)3 * NTOT * sizeof(float), stream);
        edge_pass1_f<<<eb, 256, 0, stream>>>(src, dst, nf, S0, S1, n_edges);
        node1_f<<<NTOT / 256, 256, 0, stream>>>(nf, S0, S1, ws1, wn1, b1, ws2, wn2, S3);
        edge_pass2_f<<<eb, 256, 0, stream>>>(src, dst, S3, S2, n_edges);
        node2_f<<<NTOT / 256, 256, 0, stream>>>(S0, S2, S1, b2, b3, out1, S3, out2);
        gemm_f<<<dim3(GK / 256, KCHUNKS), 256, 0, stream>>>(S3, w3, out2);
    }
}